// Round 1
// baseline (166.520 us; speedup 1.0000x reference)
//
#include <hip/hip_runtime.h>

// NaiveFourierKANLayer: y = cos-features @ W0^T + sin-features @ W1^T + bias
// N=32768, INPUTDIM=64, OUTDIM=256, GRIDSIZE=32 -> GEMM M=32768, N=256, K=4096
//
// R3 changes vs R2 (111.4 us gemm, MfmaUtil 25.7, VALUBusy 44.7, conflicts 0):
//  - LDS double-buffering with ONE barrier per K-step (T3 minimum 2-phase):
//    per kt: issue gl_lds B(t+1) -> buf^1, MFMA on buf (hides load latency),
//    features(t+1) -> ds_write buf^1, single __syncthreads().
//    Removes the stage->sync->MFMA->sync serialization (the ~50% dead time:
//    MfmaUtil 26% + non-MFMA VALU ~19% left half the kernel in barrier drain).
//  - All kt-invariant addressing (B src pointers, A-granule idx, fragment
//    granules) hoisted out of the K-loop.
//  - LDS 32KB -> 64KB per block; still 2 blocks/CU (128KB < 160KB).

#define IDIM 64
#define ODIM 256
#define KDIM 4096

typedef __attribute__((ext_vector_type(8))) unsigned short ushort8_t;
typedef __bf16 bf16x8 __attribute__((ext_vector_type(8)));
typedef float floatx4 __attribute__((ext_vector_type(4)));
typedef float floatx2 __attribute__((ext_vector_type(2)));
typedef unsigned int uintx4 __attribute__((ext_vector_type(4)));

__device__ __forceinline__ unsigned short f2bf_rne(float f) {
  unsigned int u = __float_as_uint(f);
  return (unsigned short)((u + 0x7FFFu + ((u >> 16) & 1u)) >> 16);
}

// pack two fp32 -> packed bf16 pair (lo = a, hi = b)
#if __has_builtin(__builtin_amdgcn_cvt_pk_bf16_f32)
__device__ __forceinline__ unsigned int pack2bf(float a, float b) {
  auto v = __builtin_amdgcn_cvt_pk_bf16_f32(a, b);
  unsigned int r;
  __builtin_memcpy(&r, &v, 4);
  return r;
}
#else
__device__ __forceinline__ unsigned int pack2bf(float a, float b) {
  unsigned int ua = __float_as_uint(a) + 0x8000u;  // round-half-up
  unsigned int ub = __float_as_uint(b) + 0x8000u;
  return __builtin_amdgcn_perm(ub, ua, 0x07060302u);  // {hi16(b),hi16(a)}
}
#endif

__device__ __forceinline__ void gl_lds16(const void* g, void* l) {
  __builtin_amdgcn_global_load_lds(
      (__attribute__((address_space(1))) void*)g,
      (__attribute__((address_space(3))) void*)l, 16, 0, 0);
}

// ---- weight gather+convert: fc(2,256,64,32) fp32 -> Wr(256,4096) bf16 ----
__global__ void __launch_bounds__(256) wconv(const float* __restrict__ fc,
                                             unsigned short* __restrict__ Wr) {
  int e = (blockIdx.x * 256 + threadIdx.x) << 2;  // element idx, 4 per thread
  int o = e >> 12;
  int k = e & 4095;
  int i = k >> 6;
  int c = (k >> 5) & 1;
  int g = k & 31;  // multiple of 4
  const float4 v = *(const float4*)(fc + ((size_t)c << 19) + o * 2048 + i * 32 + g);
  ushort4 r;
  r.x = f2bf_rne(v.x);
  r.y = f2bf_rne(v.y);
  r.z = f2bf_rne(v.z);
  r.w = f2bf_rne(v.w);
  *(ushort4*)(Wr + e) = r;
}

// ---- fused feature-gen + GEMM, double-buffered 2-phase pipeline ----
__global__ void __launch_bounds__(256) fkan_gemm(const float* __restrict__ X,
                                                 const unsigned short* __restrict__ Wr,
                                                 const float* __restrict__ bias,
                                                 float* __restrict__ out) {
  __shared__ __align__(16) unsigned short As[2][128 * 64];  // [m][k] XOR-swizzled
  __shared__ __align__(16) unsigned short Bs[2][128 * 64];  // [n][k] XOR-swizzled

  const int t = threadIdx.x;
  const int wv = t >> 6;        // wave 0..3
  const int ln = t & 63;
  const int lm = ln & 15;
  const int quad = ln >> 4;
  const int wm = wv >> 1;       // wave m-half
  const int wn = wv & 1;        // wave n-half
  const int m0 = blockIdx.y * 128;
  const int n0 = blockIdx.x * 128;

  // A-staging role: one row per thread, half of g-range per p
  const int arow = t & 127;
  const int p = t >> 7;  // 0: g=1..16, 1: g=17..32
  const float gstart = (float)(16 * p + 1);

  // B-staging: swizzled source so LDS image granule l holds
  // (row = l>>3, chunk = (l&7)^((l>>3)&7))
  const int brow_off = ln >> 3;
  const int bchunk = (ln & 7) ^ ((ln >> 3) & 7);

  // kt-invariant B source pointers, one per region
  const unsigned short* bsrc[4];
#pragma unroll
  for (int j = 0; j < 4; ++j) {
    int region = wv * 4 + j;
    int rowB = region * 8 + brow_off;
    bsrc[j] = Wr + (size_t)(n0 + rowB) * KDIM + bchunk * 8;
  }

  // kt-invariant A-granule (swizzled) write indices
  const int sw = arow & 7;
  const int gb = arow * 8;
  const int ga0 = gb + ((2 * p + 0) ^ sw);
  const int ga1 = gb + ((2 * p + 1) ^ sw);
  const int ga2 = gb + ((4 + 2 * p) ^ sw);
  const int ga3 = gb + ((5 + 2 * p) ^ sw);

  floatx4 acc[4][4];
#pragma unroll
  for (int a = 0; a < 4; ++a)
#pragma unroll
    for (int b = 0; b < 4; ++b)
      acc[a][b] = (floatx4){0.0f, 0.0f, 0.0f, 0.0f};

  const float* xptr = X + (size_t)(m0 + arow) * IDIM;

  // ---- B staging: async global->LDS into buffer `buf` for k-tile `ktn`
  auto stageB = [&](int ktn, int buf) {
#pragma unroll
    for (int j = 0; j < 4; ++j) {
      int region = wv * 4 + j;
      gl_lds16(bsrc[j] + ktn * 64, &Bs[buf][region * 512]);
    }
  };

  // ---- A staging: Fourier features via two packed chains (even/odd g, 2x step)
  auto features = [&](float xv, int buf) {
    float u = xv * 0.15915494309189535f;  // revolutions
    float u0 = u * gstart;                // gstart*x
    float u1 = u0 + u;                    // (gstart+1)*x
    float u2 = u + u;                     // 2x
    float c2 = __builtin_amdgcn_cosf(u2);
    float s2 = __builtin_amdgcn_sinf(u2);
    floatx2 C = {__builtin_amdgcn_cosf(u0), __builtin_amdgcn_cosf(u1)};
    floatx2 S = {__builtin_amdgcn_sinf(u0), __builtin_amdgcn_sinf(u1)};
    floatx2 c2v = {c2, c2};
    floatx2 s2v = {s2, s2};
    unsigned int cpk[8], spk[8];
#pragma unroll
    for (int j = 0; j < 8; ++j) {
      cpk[j] = pack2bf(C.x, C.y);  // cos((gs+2j)x), cos((gs+2j+1)x)
      spk[j] = pack2bf(S.x, S.y);
      floatx2 t1 = C * s2v;
      floatx2 t2 = S * s2v;
      C = __builtin_elementwise_fma(C, c2v, -t2);
      S = __builtin_elementwise_fma(S, c2v, t1);
    }
    uintx4* As4 = (uintx4*)As[buf];
    As4[ga0] = (uintx4){cpk[0], cpk[1], cpk[2], cpk[3]};
    As4[ga1] = (uintx4){cpk[4], cpk[5], cpk[6], cpk[7]};
    As4[ga2] = (uintx4){spk[0], spk[1], spk[2], spk[3]};
    As4[ga3] = (uintx4){spk[4], spk[5], spk[6], spk[7]};
  };

  // ---- MFMA on buffer `buf`: 2 k-halves x 16 MFMAs
  auto domfma = [&](int buf) {
#pragma unroll
    for (int kh = 0; kh < 2; ++kh) {
      bf16x8 af[4], bfr[4];
#pragma unroll
      for (int mt = 0; mt < 4; ++mt) {
        int r = wm * 64 + mt * 16 + lm;
        int gran = r * 8 + ((kh * 4 + quad) ^ (r & 7));
        af[mt] = __builtin_bit_cast(bf16x8, ((const ushort8_t*)As[buf])[gran]);
      }
#pragma unroll
      for (int nt = 0; nt < 4; ++nt) {
        int n = wn * 64 + nt * 16 + lm;
        int gran = n * 8 + ((kh * 4 + quad) ^ (n & 7));
        bfr[nt] = __builtin_bit_cast(bf16x8, ((const ushort8_t*)Bs[buf])[gran]);
      }
#pragma unroll
      for (int mt = 0; mt < 4; ++mt)
#pragma unroll
        for (int nt = 0; nt < 4; ++nt)
          acc[mt][nt] = __builtin_amdgcn_mfma_f32_16x16x32_bf16(
              af[mt], bfr[nt], acc[mt][nt], 0, 0, 0);
    }
  };

  // ---- prologue: fill buffer 0 with k-tile 0
  stageB(0, 0);
  features(xptr[0], 0);
  __syncthreads();  // drains vmcnt (gl_lds) + lgkmcnt (ds_write)

  // ---- steady state: one barrier per k-step
  for (int kt = 0; kt < IDIM - 1; ++kt) {
    const int cur = kt & 1;
    const int nxt = cur ^ 1;
    float xn = xptr[kt + 1];     // L1-resident after first touches
    stageB(kt + 1, nxt);         // async loads in flight across the MFMA phase
    domfma(cur);                 // 32 MFMAs hide gl_lds + x-load latency
    features(xn, nxt);           // VALU + ds_write after MFMA issue
    __syncthreads();             // single drain point per iteration
  }
  domfma((IDIM - 1) & 1);        // last tile, no prefetch

  // ---- epilogue: C[row][col] = acc + bias, verified C/D layout ----
#pragma unroll
  for (int nt = 0; nt < 4; ++nt) {
    int col = n0 + wn * 64 + nt * 16 + lm;
    float bv = bias[col];
#pragma unroll
    for (int mt = 0; mt < 4; ++mt) {
      int rbase = m0 + wm * 64 + mt * 16 + quad * 4;
#pragma unroll
      for (int r = 0; r < 4; ++r)
        out[(size_t)(rbase + r) * ODIM + col] = acc[mt][nt][r] + bv;
    }
  }
}

extern "C" void kernel_launch(void* const* d_in, const int* in_sizes, int n_in,
                              void* d_out, int out_size, void* d_ws, size_t ws_size,
                              hipStream_t stream) {
  const float* x = (const float*)d_in[0];
  const float* fc = (const float*)d_in[1];
  const float* bias = (const float*)d_in[2];
  float* out = (float*)d_out;
  unsigned short* Wr = (unsigned short*)d_ws;  // 2 MB of workspace

  hipLaunchKernelGGL(wconv, dim3(1024), dim3(256), 0, stream, fc, Wr);
  hipLaunchKernelGGL(fkan_gemm, dim3(2, 256), dim3(256), 0, stream, x, Wr, bias, out);
}

// Round 2
// 149.802 us; speedup vs baseline: 1.1116x; 1.1116x over previous
//
#include <hip/hip_runtime.h>

// NaiveFourierKANLayer: y = cos-features @ W0^T + sin-features @ W1^T + bias
// N=32768, INPUTDIM=64, OUTDIM=256, GRIDSIZE=32 -> GEMM M=32768, N=256, K=4096
//
// R4 changes vs R3 (115 us gemm, MfmaUtil 25.8, VALUBusy 51, conflicts 0):
//  - BN=256 (grid (1,512), BM=64): Fourier features computed ONCE per row
//    (R3 computed them twice, once per n-block). Kills the structural 2x in
//    the 51% VALUBusy.
//  - Feature gen: 4 threads/row, single chain-of-8 step-1 recurrence
//    (4 trans + 28 fma) per thread; bf16 via plain casts so the compiler
//    emits v_cvt_pk_bf16_f32 (vs 3-inst perm fallback).
//  - kt-loop unrolled x2 -> compile-time dbuf index, LDS addrs fully hoisted.
//  - LDS 80KB = As 2x8K + Bs 2x32K -> exactly 2 blocks/CU (163840B), keeps
//    cross-block barrier overlap. Wave tile stays 64x64 (4x4 frags), all
//    XOR-swizzle granule maps identical to the verified R2/R3 ones.

#define IDIM 64
#define ODIM 256
#define KDIM 4096
#define BM 64
#define BN 256

typedef __attribute__((ext_vector_type(8))) unsigned short ushort8_t;
typedef __bf16 bf16x8 __attribute__((ext_vector_type(8)));
typedef float floatx4 __attribute__((ext_vector_type(4)));

__device__ __forceinline__ unsigned short f2bf_rne(float f) {
  unsigned int u = __float_as_uint(f);
  return (unsigned short)((u + 0x7FFFu + ((u >> 16) & 1u)) >> 16);
}

__device__ __forceinline__ void gl_lds16(const void* g, void* l) {
  __builtin_amdgcn_global_load_lds(
      (__attribute__((address_space(1))) void*)g,
      (__attribute__((address_space(3))) void*)l, 16, 0, 0);
}

// ---- weight gather+convert: fc(2,256,64,32) fp32 -> Wr(256,4096) bf16 ----
__global__ void __launch_bounds__(256) wconv(const float* __restrict__ fc,
                                             unsigned short* __restrict__ Wr) {
  int e = (blockIdx.x * 256 + threadIdx.x) << 2;  // element idx, 4 per thread
  int o = e >> 12;
  int k = e & 4095;
  int i = k >> 6;
  int c = (k >> 5) & 1;
  int g = k & 31;  // multiple of 4
  const float4 v = *(const float4*)(fc + ((size_t)c << 19) + o * 2048 + i * 32 + g);
  ushort4 r;
  r.x = f2bf_rne(v.x);
  r.y = f2bf_rne(v.y);
  r.z = f2bf_rne(v.z);
  r.w = f2bf_rne(v.w);
  *(ushort4*)(Wr + e) = r;
}

// ---- fused feature-gen + GEMM ----
__global__ void __launch_bounds__(256) fkan_gemm(const float* __restrict__ X,
                                                 const unsigned short* __restrict__ Wr,
                                                 const float* __restrict__ bias,
                                                 float* __restrict__ out) {
  __shared__ __align__(16) unsigned short As[2][BM * 64];  // 2 x 8 KB
  __shared__ __align__(16) unsigned short Bs[2][BN * 64];  // 2 x 32 KB

  const int t = threadIdx.x;
  const int wv = t >> 6;   // wave 0..3
  const int ln = t & 63;
  const int lm = ln & 15;
  const int quad = ln >> 4;
  const int wn = wv;       // wave n-quadrant (wave tile 64m x 64n)
  const int m0 = blockIdx.y * BM;

  // feature role: 4 threads per row, thread q owns g = 8q+1 .. 8q+8
  const int arow = t >> 2;  // 0..63
  const int q = t & 3;
  const float g0f = (float)(8 * q + 1);

  // B-staging: swizzled source so LDS image granule l of a region holds
  // (row = l>>3, chunk = (l&7)^(l>>3))
  const int brow_off = ln >> 3;
  const int bchunk = (ln & 7) ^ (ln >> 3);
  const unsigned short* bbase =
      Wr + (size_t)(wv * 64 + brow_off) * KDIM + bchunk * 8;

  // A write granules (kt-invariant, XOR-swizzled)
  const int ga_c = arow * 8 + (q ^ (arow & 7));
  const int ga_s = arow * 8 + ((4 + q) ^ (arow & 7));

  floatx4 acc[4][4];
#pragma unroll
  for (int a = 0; a < 4; ++a)
#pragma unroll
    for (int b = 0; b < 4; ++b)
      acc[a][b] = (floatx4){0.0f, 0.0f, 0.0f, 0.0f};

  const float* xptr = X + (size_t)(m0 + arow) * IDIM;

  // ---- B staging: async global->LDS (8 regions x 1KB per thread-wave)
  auto stageB = [&](int ktn, int buf) {
#pragma unroll
    for (int j = 0; j < 8; ++j) {
      gl_lds16(bbase + (size_t)j * 8 * KDIM + ktn * 64,
               &Bs[buf][(wv * 8 + j) * 512]);
    }
  };

  // ---- A staging: chain-of-8 Fourier recurrence, one (cos,sin) granule pair
  auto features = [&](float xv, int buf) {
    const float inv2pi = 0.15915494309189535f;
    float u = xv * inv2pi;   // x in revolutions
    float u0 = u * g0f;      // g0*x in revolutions
    float c1 = __builtin_amdgcn_cosf(u);
    float s1 = __builtin_amdgcn_sinf(u);
    float C = __builtin_amdgcn_cosf(u0);
    float S = __builtin_amdgcn_sinf(u0);
    bf16x8 cb, sb;
    cb[0] = (__bf16)C;
    sb[0] = (__bf16)S;
#pragma unroll
    for (int j = 1; j < 8; ++j) {
      float Cn = __builtin_fmaf(C, c1, -(S * s1));
      float Sn = __builtin_fmaf(S, c1, (C * s1));
      C = Cn;
      S = Sn;
      cb[j] = (__bf16)C;
      sb[j] = (__bf16)S;
    }
    ushort8_t* As8 = (ushort8_t*)As[buf];
    As8[ga_c] = __builtin_bit_cast(ushort8_t, cb);
    As8[ga_s] = __builtin_bit_cast(ushort8_t, sb);
  };

  // ---- MFMA on buffer `buf`: 2 k-halves x 16 MFMAs
  auto domfma = [&](int buf) {
#pragma unroll
    for (int kh = 0; kh < 2; ++kh) {
      bf16x8 af[4], bfr[4];
#pragma unroll
      for (int mt = 0; mt < 4; ++mt) {
        int r = mt * 16 + lm;
        int gran = r * 8 + ((kh * 4 + quad) ^ (r & 7));
        af[mt] = __builtin_bit_cast(bf16x8, ((const ushort8_t*)As[buf])[gran]);
      }
#pragma unroll
      for (int nt = 0; nt < 4; ++nt) {
        int n = wn * 64 + nt * 16 + lm;
        int gran = n * 8 + ((kh * 4 + quad) ^ (n & 7));
        bfr[nt] = __builtin_bit_cast(bf16x8, ((const ushort8_t*)Bs[buf])[gran]);
      }
#pragma unroll
      for (int mt = 0; mt < 4; ++mt)
#pragma unroll
        for (int nt = 0; nt < 4; ++nt)
          acc[mt][nt] = __builtin_amdgcn_mfma_f32_16x16x32_bf16(
              af[mt], bfr[nt], acc[mt][nt], 0, 0, 0);
    }
  };

  // ---- prologue: fill buffer 0 with k-tile 0
  stageB(0, 0);
  features(xptr[0], 0);
  __syncthreads();

  // ---- steady state: unrolled x2 so dbuf index is compile-time
  for (int kt = 0; kt < 62; kt += 2) {
    {
      float xn = xptr[kt + 1];
      stageB(kt + 1, 1);   // loads in flight across MFMA+feature phase
      domfma(0);
      features(xn, 1);
      __syncthreads();
    }
    {
      float xn = xptr[kt + 2];
      stageB(kt + 2, 0);
      domfma(1);
      features(xn, 0);
      __syncthreads();
    }
  }
  {  // kt = 62
    float xn = xptr[63];
    stageB(63, 1);
    domfma(0);
    features(xn, 1);
    __syncthreads();
  }
  domfma(1);  // kt = 63, no prefetch

  // ---- epilogue: C[row][col] = acc + bias, verified C/D layout ----
#pragma unroll
  for (int nt = 0; nt < 4; ++nt) {
    int col = wn * 64 + nt * 16 + lm;
    float bv = bias[col];
#pragma unroll
    for (int mt = 0; mt < 4; ++mt) {
      int rbase = m0 + mt * 16 + quad * 4;
#pragma unroll
      for (int r = 0; r < 4; ++r)
        out[(size_t)(rbase + r) * ODIM + col] = acc[mt][nt][r] + bv;
    }
  }
}

extern "C" void kernel_launch(void* const* d_in, const int* in_sizes, int n_in,
                              void* d_out, int out_size, void* d_ws, size_t ws_size,
                              hipStream_t stream) {
  const float* x = (const float*)d_in[0];
  const float* fc = (const float*)d_in[1];
  const float* bias = (const float*)d_in[2];
  float* out = (float*)d_out;
  unsigned short* Wr = (unsigned short*)d_ws;  // 2 MB of workspace

  hipLaunchKernelGGL(wconv, dim3(1024), dim3(256), 0, stream, fc, Wr);
  hipLaunchKernelGGL(fkan_gemm, dim3(1, 512), dim3(256), 0, stream, x, Wr, bias, out);
}

// Round 3
// 138.881 us; speedup vs baseline: 1.1990x; 1.0786x over previous
//
#include <hip/hip_runtime.h>

// NaiveFourierKANLayer: y = cos-features @ W0^T + sin-features @ W1^T + bias
// N=32768, INPUTDIM=64, OUTDIM=256, GRIDSIZE=32 -> GEMM M=32768, N=256, K=4096
//
// R5 changes vs R4 (92.4 us gemm, MfmaUtil 30.8, VALUBusy 33.9, conflicts 2.1M):
//  - One 512-thread block per CU (grid 256, BM=128): B tile staged ONCE per CU
//    (R4's two 256-thr blocks per CU each staged the identical BN=256 B slice)
//    -> gl_lds LDS-write traffic halved.
//  - 8 waves as 2m x 2n x 2k (split-k), wave tile 64x128 x one k-half:
//    12 ds_read_b128 per 32 MFMAs (0.375 reads/MFMA vs 0.5) -> LDS read
//    traffic -25%. LDS port was the top consumer (~55-63% busy).
//  - Split-k partials summed via one-time LDS reduction epilogue
//    (64x260-padded f32 scratch, 2 rounds by row-half; ~1% cost).
//  - All XOR-swizzle granule maps, feature recurrence, pipeline order and
//    x2 unroll identical to the R4-verified forms. LDS 96KB, 2 waves/SIMD.

#define IDIM 64
#define ODIM 256
#define KDIM 4096
#define BM 128

typedef __attribute__((ext_vector_type(8))) unsigned short ushort8_t;
typedef __bf16 bf16x8 __attribute__((ext_vector_type(8)));
typedef float floatx4 __attribute__((ext_vector_type(4)));

__device__ __forceinline__ unsigned short f2bf_rne(float f) {
  unsigned int u = __float_as_uint(f);
  return (unsigned short)((u + 0x7FFFu + ((u >> 16) & 1u)) >> 16);
}

__device__ __forceinline__ void gl_lds16(const void* g, void* l) {
  __builtin_amdgcn_global_load_lds(
      (__attribute__((address_space(1))) void*)g,
      (__attribute__((address_space(3))) void*)l, 16, 0, 0);
}

// ---- weight gather+convert: fc(2,256,64,32) fp32 -> Wr(256,4096) bf16 ----
__global__ void __launch_bounds__(256) wconv(const float* __restrict__ fc,
                                             unsigned short* __restrict__ Wr) {
  int e = (blockIdx.x * 256 + threadIdx.x) << 2;  // element idx, 4 per thread
  int o = e >> 12;
  int k = e & 4095;
  int i = k >> 6;
  int c = (k >> 5) & 1;
  int g = k & 31;  // multiple of 4
  const float4 v = *(const float4*)(fc + ((size_t)c << 19) + o * 2048 + i * 32 + g);
  ushort4 r;
  r.x = f2bf_rne(v.x);
  r.y = f2bf_rne(v.y);
  r.z = f2bf_rne(v.z);
  r.w = f2bf_rne(v.w);
  *(ushort4*)(Wr + e) = r;
}

// ---- fused feature-gen + GEMM ----
__global__ void __launch_bounds__(512, 2) fkan_gemm(const float* __restrict__ X,
                                                    const unsigned short* __restrict__ Wr,
                                                    const float* __restrict__ bias,
                                                    float* __restrict__ out) {
  // carved shared: As 2x16KB | Bs 2x32KB  (epilogue reuses front 66.5KB as f32 scratch)
  __shared__ __align__(16) unsigned char smem[98304];
  unsigned short* const AsBase = (unsigned short*)smem;            // 2 x 8192 ushorts
  unsigned short* const BsBase = (unsigned short*)(smem + 32768);  // 2 x 16384 ushorts

  const int t = threadIdx.x;
  const int wv = t >> 6;          // wave 0..7
  const int ln = t & 63;
  const int lm = ln & 15;
  const int quad = ln >> 4;
  const int wk = wv & 1;          // k-half (chunks wk*4 .. wk*4+3)
  const int wn2 = (wv >> 1) & 1;  // col-half (128 cols)
  const int wm2 = wv >> 2;        // row-half (64 rows)
  const int m0 = blockIdx.x * BM;

  // feature role: 4 threads per row, thread q owns g = 8q+1 .. 8q+8
  const int arow = t >> 2;  // 0..127
  const int q = t & 3;
  const float g0f = (float)(8 * q + 1);

  // B-staging: swizzled source so LDS region granule l holds
  // (row = l>>3, chunk = (l&7)^(l>>3)); region = wv*4+j covers 8 rows
  const int brow_off = ln >> 3;
  const int bchunk = (ln & 7) ^ (ln >> 3);
  const unsigned short* bsrc[4];
#pragma unroll
  for (int j = 0; j < 4; ++j)
    bsrc[j] = Wr + (size_t)(wv * 32 + j * 8 + brow_off) * KDIM + bchunk * 8;

  // A write granules (kt-invariant, XOR-swizzled) — verified R2/R3 formulas
  const int ga_c = arow * 8 + (q ^ (arow & 7));
  const int ga_s = arow * 8 + ((4 + q) ^ (arow & 7));

  floatx4 acc[4][8];
#pragma unroll
  for (int a = 0; a < 4; ++a)
#pragma unroll
    for (int b = 0; b < 8; ++b)
      acc[a][b] = (floatx4){0.0f, 0.0f, 0.0f, 0.0f};

  const float* xptr = X + (size_t)(m0 + arow) * IDIM;

  // ---- B staging: async global->LDS, 4 regions (1KB) per wave, 32KB total
  auto stageB = [&](int ktn, int buf) {
#pragma unroll
    for (int j = 0; j < 4; ++j)
      gl_lds16(bsrc[j] + ktn * 64, BsBase + buf * 16384 + (wv * 4 + j) * 512);
  };

  // ---- A staging: chain-of-8 Fourier recurrence, one (cos,sin) granule pair
  auto features = [&](float xv, int buf) {
    const float inv2pi = 0.15915494309189535f;
    float u = xv * inv2pi;  // x in revolutions
    float u0 = u * g0f;     // g0*x in revolutions
    float c1 = __builtin_amdgcn_cosf(u);
    float s1 = __builtin_amdgcn_sinf(u);
    float C = __builtin_amdgcn_cosf(u0);
    float S = __builtin_amdgcn_sinf(u0);
    bf16x8 cb, sb;
    cb[0] = (__bf16)C;
    sb[0] = (__bf16)S;
#pragma unroll
    for (int j = 1; j < 8; ++j) {
      float Cn = __builtin_fmaf(C, c1, -(S * s1));
      float Sn = __builtin_fmaf(S, c1, (C * s1));
      C = Cn;
      S = Sn;
      cb[j] = (__bf16)C;
      sb[j] = (__bf16)S;
    }
    ushort8_t* As8 = (ushort8_t*)(AsBase + buf * 8192);
    As8[ga_c] = __builtin_bit_cast(ushort8_t, cb);
    As8[ga_s] = __builtin_bit_cast(ushort8_t, sb);
  };

  // ---- MFMA on buffer `buf`: one k-half per wave, 12 reads, 32 MFMAs
  auto domfma = [&](int buf) {
    const ushort8_t* A8 = (const ushort8_t*)(AsBase + buf * 8192);
    const ushort8_t* B8 = (const ushort8_t*)(BsBase + buf * 16384);
    const int ch = wk * 4 + quad;
    bf16x8 af[4], bfr[8];
#pragma unroll
    for (int mt = 0; mt < 4; ++mt) {
      int r = wm2 * 64 + mt * 16 + lm;
      af[mt] = __builtin_bit_cast(bf16x8, A8[r * 8 + (ch ^ (r & 7))]);
    }
#pragma unroll
    for (int nt = 0; nt < 8; ++nt) {
      int n = wn2 * 128 + nt * 16 + lm;
      bfr[nt] = __builtin_bit_cast(bf16x8, B8[n * 8 + (ch ^ (n & 7))]);
    }
#pragma unroll
    for (int mt = 0; mt < 4; ++mt)
#pragma unroll
      for (int nt = 0; nt < 8; ++nt)
        acc[mt][nt] = __builtin_amdgcn_mfma_f32_16x16x32_bf16(
            af[mt], bfr[nt], acc[mt][nt], 0, 0, 0);
  };

  // ---- prologue: fill buffer 0 with k-tile 0
  stageB(0, 0);
  features(xptr[0], 0);
  __syncthreads();

  // ---- steady state: unrolled x2 so dbuf index is compile-time
  for (int kt = 0; kt < 62; kt += 2) {
    {
      float xn = xptr[kt + 1];
      stageB(kt + 1, 1);  // loads in flight across MFMA+feature phase
      domfma(0);
      features(xn, 1);
      __syncthreads();
    }
    {
      float xn = xptr[kt + 2];
      stageB(kt + 2, 0);
      domfma(1);
      features(xn, 0);
      __syncthreads();
    }
  }
  {  // kt = 62
    float xn = xptr[63];
    stageB(63, 1);
    domfma(0);
    features(xn, 1);
    __syncthreads();
  }
  domfma(1);  // kt = 63, no prefetch

  // ---- split-k reduction + store: wk=1 partials via padded LDS scratch ----
  float* red = (float*)smem;  // [64][260] f32 = 66560 B, stride 260 -> 2-way banks
  for (int half = 0; half < 2; ++half) {
    __syncthreads();  // all waves done with As/Bs (or previous round)
    if (wk == 1 && wm2 == half) {
#pragma unroll
      for (int mt = 0; mt < 4; ++mt)
#pragma unroll
        for (int nt = 0; nt < 8; ++nt) {
          int col = wn2 * 128 + nt * 16 + lm;
#pragma unroll
          for (int idx = 0; idx < 4; ++idx)
            red[(mt * 16 + quad * 4 + idx) * 260 + col] = acc[mt][nt][idx];
        }
    }
    __syncthreads();
    if (wk == 0 && wm2 == half) {
#pragma unroll
      for (int nt = 0; nt < 8; ++nt) {
        int col = wn2 * 128 + nt * 16 + lm;
        float bv = bias[col];
#pragma unroll
        for (int mt = 0; mt < 4; ++mt) {
          int rbase = m0 + half * 64 + mt * 16 + quad * 4;
#pragma unroll
          for (int idx = 0; idx < 4; ++idx)
            out[(size_t)(rbase + idx) * ODIM + col] =
                acc[mt][nt][idx] + red[(mt * 16 + quad * 4 + idx) * 260 + col] + bv;
        }
      }
    }
  }
}

extern "C" void kernel_launch(void* const* d_in, const int* in_sizes, int n_in,
                              void* d_out, int out_size, void* d_ws, size_t ws_size,
                              hipStream_t stream) {
  const float* x = (const float*)d_in[0];
  const float* fc = (const float*)d_in[1];
  const float* bias = (const float*)d_in[2];
  float* out = (float*)d_out;
  unsigned short* Wr = (unsigned short*)d_ws;  // 2 MB of workspace

  hipLaunchKernelGGL(wconv, dim3(1024), dim3(256), 0, stream, fc, Wr);
  hipLaunchKernelGGL(fkan_gemm, dim3(256), dim3(512), 0, stream, x, Wr, bias, out);
}